// Round 5
// baseline (216.770 us; speedup 1.0000x reference)
//
#include <hip/hip_runtime.h>

typedef unsigned short u16;
typedef __bf16 bf16x8 __attribute__((ext_vector_type(8)));
typedef float f32x4 __attribute__((ext_vector_type(4)));

#define BB 2
#define TT 2048
#define CC 1024
#define HH 16
#define DD 64
#define MM (BB*TT)   // 4096

__device__ __forceinline__ u16 f2b(float f) {
    union { float f; unsigned int i; } a; a.f = f;
    unsigned int u = a.i;
    unsigned int r = (u + 0x7FFFu + ((u >> 16) & 1u)) >> 16;
    return (u16)r;
}
__device__ __forceinline__ u16 f2b_fast(float f) {
    union { float f; unsigned int i; } a; a.f = f;
    return (u16)((a.i + 0x8000u) >> 16);
}

// async global -> LDS, 16B per lane (dest must be wave-uniform base + lane*16)
__device__ __forceinline__ void gld16(const u16* g, u16* l) {
    __builtin_amdgcn_global_load_lds(
        (const __attribute__((address_space(1))) unsigned int*)g,
        (__attribute__((address_space(3))) unsigned int*)l, 16, 0, 0);
}

// ---------------- fp32 -> bf16 elementwise ----------------
__global__ __launch_bounds__(256) void cvt_x_k(const float* __restrict__ in,
                                               u16* __restrict__ out) {
    int i = blockIdx.x * 256 + threadIdx.x;
    float4 v = ((const float4*)in)[i];
    ushort4 o;
    o.x = f2b(v.x); o.y = f2b(v.y); o.z = f2b(v.z); o.w = f2b(v.w);
    ((ushort4*)out)[i] = o;
}

// ------ fp32 [K,N] -> bf16 [N,K] transpose+convert ------
__global__ __launch_bounds__(256) void transpose_cvt_k(const float* __restrict__ in,
                                                       u16* __restrict__ out,
                                                       int K, int N) {
    __shared__ u16 tile[64][65];
    int n0 = blockIdx.x * 64, k0 = blockIdx.y * 64;
    int tx = threadIdx.x, ty = threadIdx.y;   // (64,4)
    for (int i = 0; i < 16; i++) {
        int row = ty + i * 4;
        tile[row][tx] = f2b(in[(size_t)(k0 + row) * N + n0 + tx]);
    }
    __syncthreads();
    for (int i = 0; i < 16; i++) {
        int row = ty + i * 4;
        out[(size_t)(n0 + row) * K + k0 + tx] = tile[tx][row];
    }
}

// ------ bf16 per-bh transpose: v[bh][T][D] -> vt[bh][D][T] ------
__global__ __launch_bounds__(256) void transpose_v_k(const u16* __restrict__ in,
                                                     u16* __restrict__ out) {
    __shared__ u16 tile[64][65];
    int t0 = blockIdx.x * 64, bh = blockIdx.y;
    const u16* src = in + (size_t)bh * TT * DD;
    u16* dst = out + (size_t)bh * DD * TT;
    int tx = threadIdx.x, ty = threadIdx.y;
    for (int i = 0; i < 16; i++) {
        int row = ty + i * 4;
        tile[row][tx] = src[(size_t)(t0 + row) * DD + tx];
    }
    __syncthreads();
    for (int i = 0; i < 16; i++) {
        int row = ty + i * 4;
        dst[(size_t)row * TT + t0 + tx] = tile[tx][row];
    }
}

// ---------------- GEMM: C[M,N] = A[M,K] * Bt[N,K]^T ----------------
// MODE 0 epilogue pre-scales q by 0.125*log2(e) for the attn log2-softmax.
template<int MODE>
__global__ __launch_bounds__(256) void gemm_k(const u16* __restrict__ A,
                                              const u16* __restrict__ Bt,
                                              u16* __restrict__ Cq,
                                              u16* __restrict__ Ck,
                                              u16* __restrict__ Cv,
                                              float* __restrict__ Cout,
                                              int N, int K) {
    __shared__ __attribute__((aligned(16))) u16 As[128 * 32];
    __shared__ __attribute__((aligned(16))) u16 Bs[128 * 32];
    const int tid  = threadIdx.x;
    const int lane = tid & 63, w = tid >> 6;
    const int wm = w >> 1, wn = w & 1;
    const int quad = lane >> 4, l16 = lane & 15;
    const int m0 = blockIdx.x * 128, n0 = blockIdx.y * 128;

    f32x4 acc[4][4];
    for (int mi = 0; mi < 4; mi++)
        for (int ni = 0; ni < 4; ni++)
            for (int e = 0; e < 4; e++) acc[mi][ni][e] = 0.f;

    for (int k0 = 0; k0 < K; k0 += 32) {
        for (int i = 0; i < 2; i++) {
            int c = tid + 256 * i;
            int row = c >> 2, col = (c & 3) * 8;
            const u16* srcA;
            if constexpr (MODE == 0) {
                srcA = A + (size_t)(m0 + row) * K + k0 + col;
            } else {
                int m = m0 + row;
                int b = m >> 11, t = m & 2047;
                int kk = k0 + col;
                int h = kk >> 6, d = kk & 63;
                srcA = A + ((size_t)(b * HH + h) * TT + t) * DD + d;
            }
            gld16(srcA, &As[c * 8]);
            gld16(Bt + (size_t)(n0 + row) * K + k0 + col, &Bs[c * 8]);
        }
        __syncthreads();
        bf16x8 af[4], bfm[4];
        for (int mi = 0; mi < 4; mi++)
            af[mi] = *(const bf16x8*)&As[(wm * 64 + mi * 16 + l16) * 32 + quad * 8];
        for (int ni = 0; ni < 4; ni++)
            bfm[ni] = *(const bf16x8*)&Bs[(wn * 64 + ni * 16 + l16) * 32 + quad * 8];
        for (int mi = 0; mi < 4; mi++)
            for (int ni = 0; ni < 4; ni++)
                acc[mi][ni] = __builtin_amdgcn_mfma_f32_16x16x32_bf16(
                    af[mi], bfm[ni], acc[mi][ni], 0, 0, 0);
        __syncthreads();
    }

    const float SCQ = 0.125f * 1.44269504f;
    for (int mi = 0; mi < 4; mi++)
        for (int ni = 0; ni < 4; ni++)
            for (int r = 0; r < 4; r++) {
                int row = m0 + wm * 64 + mi * 16 + quad * 4 + r;
                int col = n0 + wn * 64 + ni * 16 + l16;
                if constexpr (MODE == 0) {
                    int which = col >> 10;
                    int h = (col >> 6) & 15, d = col & 63;
                    int b = row >> 11, t = row & 2047;
                    size_t off = ((size_t)(b * HH + h) * TT + t) * DD + d;
                    float val = acc[mi][ni][r];
                    if (which == 0) val *= SCQ;
                    (which == 0 ? Cq : which == 1 ? Ck : Cv)[off] = f2b(val);
                } else {
                    Cout[(size_t)row * N + col] = acc[mi][ni][r];
                }
            }
}

// ---------------- flash attention v9: 512-thread blocks, 128 q-rows, 4 waves/SIMD ----------------
// R4 lesson: V-dbuf neutral; real limiter = 2 waves/SIMD (LDS-bound occupancy)
// exposing dependent-chain latency. v9: block covers an sb-PAIR (2j, 2j+1) --
// both need nkt = j+1 passes, so one uniform K-loop. 8 waves x 16 q-rows.
// K/V tiles now shared by 8 waves (staging per wave halves). LDS = 32K (K dbuf)
// + 16K (V single) + 32K (Ps) = 80 KB -> 2 blocks/CU = 16 waves = 4 waves/SIMD.
// Grid (256, 2): CU c hosts (c, y=0) work 16-jj and (c, y=1) work jj+1 -> 17
// passes/CU, exact balance; both share bh = c&31 -> same K/V in L1/L2;
// XCD = bh%8 keeps each head's K/V in one XCD L2.
// V single-buffer B2 drain is covered by the co-resident block (4 waves/SIMD).
__global__ __launch_bounds__(512, 4) void attn_k(const u16* __restrict__ Q,
                                                 const u16* __restrict__ Kb,
                                                 const u16* __restrict__ Vtg,
                                                 u16* __restrict__ Y) {
    __shared__ __attribute__((aligned(16))) u16 Ks[2][128 * 64];  // 32 KB
    __shared__ __attribute__((aligned(16))) u16 Vs[64 * 128];     // 16 KB
    __shared__ __attribute__((aligned(16))) u16 Ps[8][16 * 128];  // 32 KB
    const int tid  = threadIdx.x;
    const int lane = tid & 63, w = tid >> 6;       // w = 0..7
    const int quad = lane >> 4, l16 = lane & 15;
    const int bh = blockIdx.x & 31;                // consecutive blocks same XCD path
    const int jj = blockIdx.x >> 5;                // 0..7
    const int j  = blockIdx.y ? jj : 15 - jj;      // q-block 0..15; CU sum = 17 passes
    const int nkt = j + 1;
    const size_t base  = (size_t)bh * TT * DD;
    const size_t baseV = (size_t)bh * DD * TT;

    // per-lane staging offsets: 2 rounds x 512 lanes cover 1024 16B-slots/tile.
    // content swizzle: LDS slot s of row holds global col-group s^(row&7).
    int ksidx[2], koff[2], voff[2];
    for (int r = 0; r < 2; r++) {
        int sidx = r * 512 + tid;
        ksidx[r] = sidx;
        int kr = sidx >> 3, ksl = sidx & 7;
        koff[r] = kr * 64 + ((ksl ^ (kr & 7)) << 3);
        int vr = sidx >> 4, vsl = sidx & 15;
        voff[r] = vr * TT + ((vsl ^ (vr & 7)) << 3);
    }
    const u16* kg = Kb + base;      // + jk*8192 + koff[r]
    const u16* vg = Vtg + baseV;    // + jk*128  + voff[r]

    // prologue: stage tile 0
    for (int r = 0; r < 2; r++) gld16(kg + koff[r], &Ks[0][ksidx[r] * 8]);
    for (int r = 0; r < 2; r++) gld16(vg + voff[r], &Vs[ksidx[r] * 8]);

    // Q fragments (A-layout, pre-scaled by 0.125*log2e in gemm0 epilogue)
    bf16x8 qf[2];
    for (int kk = 0; kk < 2; kk++)
        qf[kk] = *(const bf16x8*)(Q + base +
            (size_t)(j * 128 + w * 16 + l16) * DD + kk * 32 + quad * 8);

    // ds_read swizzled slot offsets (u16 elements)
    const int swx = (l16 & 7);
    const int swk0 = ((quad ^ swx) << 3);
    const int swk1 = (((4 + quad) ^ swx) << 3);

    float mst[4], lst[4];
    f32x4 oacc[4];
    for (int r = 0; r < 4; r++) { mst[r] = -1e30f; lst[r] = 0.f; }
    for (int nd = 0; nd < 4; nd++)
        for (int e = 0; e < 4; e++) oacc[nd][e] = 0.f;

    for (int jk = 0; jk < nkt; jk++) {
        const int cb = jk & 1;
        __syncthreads();   // B1: stage(jk) visible; Ks[cb^1] free

        // stage next K tile (full pass of cover before next B1 drain)
        if (jk + 1 < nkt) {
            const u16* kn = kg + (size_t)(jk + 1) * (128 * DD);
            for (int r = 0; r < 2; r++)
                gld16(kn + koff[r], &Ks[cb ^ 1][ksidx[r] * 8]);
        }

        // ---- S = Q K^T from LDS (swizzled ds_read_b128) ----
        f32x4 s[8];
        for (int ni = 0; ni < 8; ni++)
            for (int e = 0; e < 4; e++) s[ni][e] = 0.f;
        {
            bf16x8 kfa[8];
            for (int ni = 0; ni < 8; ni++)
                kfa[ni] = *(const bf16x8*)&Ks[cb][(ni * 16 + l16) * 64 + swk0];
            for (int ni = 0; ni < 8; ni++)
                s[ni] = __builtin_amdgcn_mfma_f32_16x16x32_bf16(
                    qf[0], kfa[ni], s[ni], 0, 0, 0);
        }
        {
            bf16x8 kfa[8];
            for (int ni = 0; ni < 8; ni++)
                kfa[ni] = *(const bf16x8*)&Ks[cb][(ni * 16 + l16) * 64 + swk1];
            for (int ni = 0; ni < 8; ni++)
                s[ni] = __builtin_amdgcn_mfma_f32_16x16x32_bf16(
                    qf[1], kfa[ni], s[ni], 0, 0, 0);
        }

        // ---- online softmax (log2 domain) + Ps write ----
        if (jk == j) {                         // diagonal tile: causal mask
            int row0 = j * 128 + w * 16 + quad * 4;
            int col0 = jk * 128 + l16;
            for (int ni = 0; ni < 8; ni++)
                for (int r = 0; r < 4; r++)
                    if (col0 + ni * 16 > row0 + r) s[ni][r] = -1e30f;
        }
        float alpha[4];
        for (int r = 0; r < 4; r++) {
            float mx = s[0][r];
            for (int ni = 1; ni < 8; ni++) mx = fmaxf(mx, s[ni][r]);
            for (int off = 8; off >= 1; off >>= 1)
                mx = fmaxf(mx, __shfl_xor(mx, off));
            float mn = fmaxf(mst[r], mx);
            alpha[r] = __builtin_amdgcn_exp2f(mst[r] - mn);
            mst[r] = mn;
        }
        float rs[4] = {0.f, 0.f, 0.f, 0.f};
        for (int ni = 0; ni < 8; ni++)
            for (int r = 0; r < 4; r++) {
                float pv = __builtin_amdgcn_exp2f(s[ni][r] - mst[r]);
                rs[r] += pv;
                int row = quad * 4 + r;
                int cg  = ni * 2 + (l16 >> 3);
                Ps[w][row * 128 + ((cg ^ row) << 3) + (l16 & 7)] = f2b_fast(pv);
            }
        for (int r = 0; r < 4; r++) {
            float sm = rs[r];
            for (int off = 8; off >= 1; off >>= 1)
                sm += __shfl_xor(sm, off);
            lst[r] = lst[r] * alpha[r] + sm;
            for (int nd = 0; nd < 4; nd++) oacc[nd][r] *= alpha[r];
        }

        // ---- O += P V from LDS ----
        for (int kk = 0; kk < 4; kk++) {
            const int swv = (((kk * 4 + quad) ^ swx) << 3);
            bf16x8 vfa[4];
            for (int nd = 0; nd < 4; nd++)
                vfa[nd] = *(const bf16x8*)&Vs[(nd * 16 + l16) * 128 + swv];
            bf16x8 pf = *(const bf16x8*)&Ps[w][l16 * 128 +
                (((kk * 4 + quad) ^ l16) << 3)];
            for (int nd = 0; nd < 4; nd++)
                oacc[nd] = __builtin_amdgcn_mfma_f32_16x16x32_bf16(
                    pf, vfa[nd], oacc[nd], 0, 0, 0);
        }

        // ---- B2 + stage next V tile (single buffer; readers done; drain
        //      covered by the co-resident block's waves at 4 waves/SIMD) ----
        if (jk + 1 < nkt) {
            __syncthreads();
            const u16* vn = vg + (size_t)(jk + 1) * 128;
            for (int r = 0; r < 2; r++)
                gld16(vn + voff[r], &Vs[ksidx[r] * 8]);
        }
    }

    for (int nd = 0; nd < 4; nd++)
        for (int r = 0; r < 4; r++) {
            int row = j * 128 + w * 16 + quad * 4 + r;
            int col = nd * 16 + l16;
            Y[base + (size_t)row * DD + col] = f2b(oacc[nd][r] / lst[r]);
        }
}

extern "C" void kernel_launch(void* const* d_in, const int* in_sizes, int n_in,
                              void* d_out, int out_size, void* d_ws, size_t ws_size,
                              hipStream_t stream) {
    const float* x      = (const float*)d_in[0];   // [2,2048,1024] fp32
    const float* W_attn = (const float*)d_in[1];   // [1024,3072]  fp32
    const float* W_proj = (const float*)d_in[2];   // [1024,1024]  fp32
    float* out = (float*)d_out;                    // [2,2048,1024] fp32

    u16* Wt_attn = (u16*)d_ws;                    // 3072*1024
    u16* Wt_proj = Wt_attn + 3072 * 1024;         // 1024*1024
    u16* xb      = Wt_proj + 1024 * 1024;         // 4096*1024 (reused as vt)
    u16* q       = xb + (size_t)MM * CC;
    u16* k       = q + (size_t)32 * 2048 * 64;
    u16* v       = k + (size_t)32 * 2048 * 64;
    u16* y       = v + (size_t)32 * 2048 * 64;
    u16* vt      = xb;                            // dead after gemm<0>

    cvt_x_k<<<dim3(MM * CC / 1024), 256, 0, stream>>>(x, xb);
    transpose_cvt_k<<<dim3(3072 / 64, 1024 / 64), dim3(64, 4), 0, stream>>>(
        W_attn, Wt_attn, 1024, 3072);
    transpose_cvt_k<<<dim3(1024 / 64, 1024 / 64), dim3(64, 4), 0, stream>>>(
        W_proj, Wt_proj, 1024, 1024);
    gemm_k<0><<<dim3(MM / 128, 3072 / 128), 256, 0, stream>>>(
        xb, Wt_attn, q, k, v, nullptr, 3072, 1024);
    transpose_v_k<<<dim3(TT / 64, BB * HH), dim3(64, 4), 0, stream>>>(v, vt);
    attn_k<<<dim3(256, 2), 512, 0, stream>>>(q, k, vt, y);
    gemm_k<1><<<dim3(MM / 128, 1024 / 128), 256, 0, stream>>>(
        y, Wt_proj, nullptr, nullptr, nullptr, out, 1024, 1024);
}

// Round 6
// 212.384 us; speedup vs baseline: 1.0207x; 1.0207x over previous
//
#include <hip/hip_runtime.h>

typedef unsigned short u16;
typedef __bf16 bf16x8 __attribute__((ext_vector_type(8)));
typedef float f32x4 __attribute__((ext_vector_type(4)));

#define BB 2
#define TT 2048
#define CC 1024
#define HH 16
#define DD 64
#define MM (BB*TT)   // 4096

__device__ __forceinline__ u16 f2b(float f) {
    union { float f; unsigned int i; } a; a.f = f;
    unsigned int u = a.i;
    unsigned int r = (u + 0x7FFFu + ((u >> 16) & 1u)) >> 16;
    return (u16)r;
}
__device__ __forceinline__ u16 f2b_fast(float f) {
    union { float f; unsigned int i; } a; a.f = f;
    return (u16)((a.i + 0x8000u) >> 16);
}

// async global -> LDS, 16B per lane (dest must be wave-uniform base + lane*16)
__device__ __forceinline__ void gld16(const u16* g, u16* l) {
    __builtin_amdgcn_global_load_lds(
        (const __attribute__((address_space(1))) unsigned int*)g,
        (__attribute__((address_space(3))) unsigned int*)l, 16, 0, 0);
}

// ---------------- fp32 -> bf16 elementwise ----------------
__global__ __launch_bounds__(256) void cvt_x_k(const float* __restrict__ in,
                                               u16* __restrict__ out) {
    int i = blockIdx.x * 256 + threadIdx.x;
    float4 v = ((const float4*)in)[i];
    ushort4 o;
    o.x = f2b(v.x); o.y = f2b(v.y); o.z = f2b(v.z); o.w = f2b(v.w);
    ((ushort4*)out)[i] = o;
}

// ------ fp32 [K,N] -> bf16 [N,K] transpose+convert ------
__global__ __launch_bounds__(256) void transpose_cvt_k(const float* __restrict__ in,
                                                       u16* __restrict__ out,
                                                       int K, int N) {
    __shared__ u16 tile[64][65];
    int n0 = blockIdx.x * 64, k0 = blockIdx.y * 64;
    int tx = threadIdx.x, ty = threadIdx.y;   // (64,4)
    for (int i = 0; i < 16; i++) {
        int row = ty + i * 4;
        tile[row][tx] = f2b(in[(size_t)(k0 + row) * N + n0 + tx]);
    }
    __syncthreads();
    for (int i = 0; i < 16; i++) {
        int row = ty + i * 4;
        out[(size_t)(n0 + row) * K + k0 + tx] = tile[tx][row];
    }
}

// ------ bf16 per-bh transpose: v[bh][T][D] -> vt[bh][D][T] ------
__global__ __launch_bounds__(256) void transpose_v_k(const u16* __restrict__ in,
                                                     u16* __restrict__ out) {
    __shared__ u16 tile[64][65];
    int t0 = blockIdx.x * 64, bh = blockIdx.y;
    const u16* src = in + (size_t)bh * TT * DD;
    u16* dst = out + (size_t)bh * DD * TT;
    int tx = threadIdx.x, ty = threadIdx.y;
    for (int i = 0; i < 16; i++) {
        int row = ty + i * 4;
        tile[row][tx] = src[(size_t)(t0 + row) * DD + tx];
    }
    __syncthreads();
    for (int i = 0; i < 16; i++) {
        int row = ty + i * 4;
        dst[(size_t)row * TT + t0 + tx] = tile[tx][row];
    }
}

// ---------------- GEMM: C[M,N] = A[M,K] * Bt[N,K]^T ----------------
// MODE 0 epilogue pre-scales q by 0.125*log2(e) for the attn log2-softmax.
template<int MODE>
__global__ __launch_bounds__(256) void gemm_k(const u16* __restrict__ A,
                                              const u16* __restrict__ Bt,
                                              u16* __restrict__ Cq,
                                              u16* __restrict__ Ck,
                                              u16* __restrict__ Cv,
                                              float* __restrict__ Cout,
                                              int N, int K) {
    __shared__ __attribute__((aligned(16))) u16 As[128 * 32];
    __shared__ __attribute__((aligned(16))) u16 Bs[128 * 32];
    const int tid  = threadIdx.x;
    const int lane = tid & 63, w = tid >> 6;
    const int wm = w >> 1, wn = w & 1;
    const int quad = lane >> 4, l16 = lane & 15;
    const int m0 = blockIdx.x * 128, n0 = blockIdx.y * 128;

    f32x4 acc[4][4];
    for (int mi = 0; mi < 4; mi++)
        for (int ni = 0; ni < 4; ni++)
            for (int e = 0; e < 4; e++) acc[mi][ni][e] = 0.f;

    for (int k0 = 0; k0 < K; k0 += 32) {
        for (int i = 0; i < 2; i++) {
            int c = tid + 256 * i;
            int row = c >> 2, col = (c & 3) * 8;
            const u16* srcA;
            if constexpr (MODE == 0) {
                srcA = A + (size_t)(m0 + row) * K + k0 + col;
            } else {
                int m = m0 + row;
                int b = m >> 11, t = m & 2047;
                int kk = k0 + col;
                int h = kk >> 6, d = kk & 63;
                srcA = A + ((size_t)(b * HH + h) * TT + t) * DD + d;
            }
            gld16(srcA, &As[c * 8]);
            gld16(Bt + (size_t)(n0 + row) * K + k0 + col, &Bs[c * 8]);
        }
        __syncthreads();
        bf16x8 af[4], bfm[4];
        for (int mi = 0; mi < 4; mi++)
            af[mi] = *(const bf16x8*)&As[(wm * 64 + mi * 16 + l16) * 32 + quad * 8];
        for (int ni = 0; ni < 4; ni++)
            bfm[ni] = *(const bf16x8*)&Bs[(wn * 64 + ni * 16 + l16) * 32 + quad * 8];
        for (int mi = 0; mi < 4; mi++)
            for (int ni = 0; ni < 4; ni++)
                acc[mi][ni] = __builtin_amdgcn_mfma_f32_16x16x32_bf16(
                    af[mi], bfm[ni], acc[mi][ni], 0, 0, 0);
        __syncthreads();
    }

    const float SCQ = 0.125f * 1.44269504f;
    for (int mi = 0; mi < 4; mi++)
        for (int ni = 0; ni < 4; ni++)
            for (int r = 0; r < 4; r++) {
                int row = m0 + wm * 64 + mi * 16 + quad * 4 + r;
                int col = n0 + wn * 64 + ni * 16 + l16;
                if constexpr (MODE == 0) {
                    int which = col >> 10;
                    int h = (col >> 6) & 15, d = col & 63;
                    int b = row >> 11, t = row & 2047;
                    size_t off = ((size_t)(b * HH + h) * TT + t) * DD + d;
                    float val = acc[mi][ni][r];
                    if (which == 0) val *= SCQ;
                    (which == 0 ? Cq : which == 1 ? Ck : Cv)[off] = f2b(val);
                } else {
                    Cout[(size_t)row * N + col] = acc[mi][ni][r];
                }
            }
}

// ---------------- flash attention v10: v9 structure, spill-free register cap ----------------
// R5 lesson (repeat of R1): __launch_bounds__ min-waves >= 3 forces VGPR to 64
// on this toolchain -> ~90-reg working set spills (WRITE_SIZE 8->22.5 MB).
// v10 = v9 with __launch_bounds__(512, 2): cap 256, allocator lands ~88-104
// (v8 measured 88 with the same per-wave body). At <=128 VGPR the HW runs
// 4 waves/SIMD whenever both LDS-permitted blocks (80 KB -> 2/CU) are resident.
// Structure: block covers an sb-PAIR (128 q-rows), 8 waves x 16 rows; K/V tiles
// shared by 8 waves; grid (256,2) balances causal work to 17 passes/CU;
// bh = blockIdx.x & 31 -> XCD = bh%8 keeps each head's K/V in one XCD L2.
__global__ __launch_bounds__(512, 2) void attn_k(const u16* __restrict__ Q,
                                                 const u16* __restrict__ Kb,
                                                 const u16* __restrict__ Vtg,
                                                 u16* __restrict__ Y) {
    __shared__ __attribute__((aligned(16))) u16 Ks[2][128 * 64];  // 32 KB
    __shared__ __attribute__((aligned(16))) u16 Vs[64 * 128];     // 16 KB
    __shared__ __attribute__((aligned(16))) u16 Ps[8][16 * 128];  // 32 KB
    const int tid  = threadIdx.x;
    const int lane = tid & 63, w = tid >> 6;       // w = 0..7
    const int quad = lane >> 4, l16 = lane & 15;
    const int bh = blockIdx.x & 31;                // XCD = bh%8 (256%8==0 keeps pairs aligned)
    const int jj = blockIdx.x >> 5;                // 0..7
    const int j  = blockIdx.y ? jj : 15 - jj;      // q-block 0..15; CU sum = 17 passes
    const int nkt = j + 1;
    const size_t base  = (size_t)bh * TT * DD;
    const size_t baseV = (size_t)bh * DD * TT;

    // per-lane staging offsets: 2 rounds x 512 lanes cover 1024 16B-slots/tile.
    // content swizzle: LDS slot s of row holds global col-group s^(row&7).
    int ksidx[2], koff[2], voff[2];
    for (int r = 0; r < 2; r++) {
        int sidx = r * 512 + tid;
        ksidx[r] = sidx;
        int kr = sidx >> 3, ksl = sidx & 7;
        koff[r] = kr * 64 + ((ksl ^ (kr & 7)) << 3);
        int vr = sidx >> 4, vsl = sidx & 15;
        voff[r] = vr * TT + ((vsl ^ (vr & 7)) << 3);
    }
    const u16* kg = Kb + base;      // + jk*8192 + koff[r]
    const u16* vg = Vtg + baseV;    // + jk*128  + voff[r]

    // prologue: stage tile 0
    for (int r = 0; r < 2; r++) gld16(kg + koff[r], &Ks[0][ksidx[r] * 8]);
    for (int r = 0; r < 2; r++) gld16(vg + voff[r], &Vs[ksidx[r] * 8]);

    // Q fragments (A-layout, pre-scaled by 0.125*log2e in gemm0 epilogue)
    bf16x8 qf[2];
    for (int kk = 0; kk < 2; kk++)
        qf[kk] = *(const bf16x8*)(Q + base +
            (size_t)(j * 128 + w * 16 + l16) * DD + kk * 32 + quad * 8);

    // ds_read swizzled slot offsets (u16 elements)
    const int swx = (l16 & 7);
    const int swk0 = ((quad ^ swx) << 3);
    const int swk1 = (((4 + quad) ^ swx) << 3);

    float mst[4], lst[4];
    f32x4 oacc[4];
    for (int r = 0; r < 4; r++) { mst[r] = -1e30f; lst[r] = 0.f; }
    for (int nd = 0; nd < 4; nd++)
        for (int e = 0; e < 4; e++) oacc[nd][e] = 0.f;

    for (int jk = 0; jk < nkt; jk++) {
        const int cb = jk & 1;
        __syncthreads();   // B1: stage(jk) visible; Ks[cb^1] free

        // stage next K tile (full pass of cover before next B1 drain)
        if (jk + 1 < nkt) {
            const u16* kn = kg + (size_t)(jk + 1) * (128 * DD);
            for (int r = 0; r < 2; r++)
                gld16(kn + koff[r], &Ks[cb ^ 1][ksidx[r] * 8]);
        }

        // ---- S = Q K^T from LDS (swizzled ds_read_b128) ----
        f32x4 s[8];
        for (int ni = 0; ni < 8; ni++)
            for (int e = 0; e < 4; e++) s[ni][e] = 0.f;
        {
            bf16x8 kfa[8];
            for (int ni = 0; ni < 8; ni++)
                kfa[ni] = *(const bf16x8*)&Ks[cb][(ni * 16 + l16) * 64 + swk0];
            for (int ni = 0; ni < 8; ni++)
                s[ni] = __builtin_amdgcn_mfma_f32_16x16x32_bf16(
                    qf[0], kfa[ni], s[ni], 0, 0, 0);
        }
        {
            bf16x8 kfa[8];
            for (int ni = 0; ni < 8; ni++)
                kfa[ni] = *(const bf16x8*)&Ks[cb][(ni * 16 + l16) * 64 + swk1];
            for (int ni = 0; ni < 8; ni++)
                s[ni] = __builtin_amdgcn_mfma_f32_16x16x32_bf16(
                    qf[1], kfa[ni], s[ni], 0, 0, 0);
        }

        // ---- online softmax (log2 domain) + Ps write ----
        if (jk == j) {                         // diagonal tile: causal mask
            int row0 = j * 128 + w * 16 + quad * 4;
            int col0 = jk * 128 + l16;
            for (int ni = 0; ni < 8; ni++)
                for (int r = 0; r < 4; r++)
                    if (col0 + ni * 16 > row0 + r) s[ni][r] = -1e30f;
        }
        float alpha[4];
        for (int r = 0; r < 4; r++) {
            float mx = s[0][r];
            for (int ni = 1; ni < 8; ni++) mx = fmaxf(mx, s[ni][r]);
            for (int off = 8; off >= 1; off >>= 1)
                mx = fmaxf(mx, __shfl_xor(mx, off));
            float mn = fmaxf(mst[r], mx);
            alpha[r] = __builtin_amdgcn_exp2f(mst[r] - mn);
            mst[r] = mn;
        }
        float rs[4] = {0.f, 0.f, 0.f, 0.f};
        for (int ni = 0; ni < 8; ni++)
            for (int r = 0; r < 4; r++) {
                float pv = __builtin_amdgcn_exp2f(s[ni][r] - mst[r]);
                rs[r] += pv;
                int row = quad * 4 + r;
                int cg  = ni * 2 + (l16 >> 3);
                Ps[w][row * 128 + ((cg ^ row) << 3) + (l16 & 7)] = f2b_fast(pv);
            }
        for (int r = 0; r < 4; r++) {
            float sm = rs[r];
            for (int off = 8; off >= 1; off >>= 1)
                sm += __shfl_xor(sm, off);
            lst[r] = lst[r] * alpha[r] + sm;
            for (int nd = 0; nd < 4; nd++) oacc[nd][r] *= alpha[r];
        }

        // ---- O += P V from LDS ----
        for (int kk = 0; kk < 4; kk++) {
            const int swv = (((kk * 4 + quad) ^ swx) << 3);
            bf16x8 vfa[4];
            for (int nd = 0; nd < 4; nd++)
                vfa[nd] = *(const bf16x8*)&Vs[(nd * 16 + l16) * 128 + swv];
            bf16x8 pf = *(const bf16x8*)&Ps[w][l16 * 128 +
                (((kk * 4 + quad) ^ l16) << 3)];
            for (int nd = 0; nd < 4; nd++)
                oacc[nd] = __builtin_amdgcn_mfma_f32_16x16x32_bf16(
                    pf, vfa[nd], oacc[nd], 0, 0, 0);
        }

        // ---- B2 + stage next V tile (single buffer; readers done; drain
        //      covered by co-resident waves at 4 waves/SIMD) ----
        if (jk + 1 < nkt) {
            __syncthreads();
            const u16* vn = vg + (size_t)(jk + 1) * 128;
            for (int r = 0; r < 2; r++)
                gld16(vn + voff[r], &Vs[ksidx[r] * 8]);
        }
    }

    for (int nd = 0; nd < 4; nd++)
        for (int r = 0; r < 4; r++) {
            int row = j * 128 + w * 16 + quad * 4 + r;
            int col = nd * 16 + l16;
            Y[base + (size_t)row * DD + col] = f2b(oacc[nd][r] / lst[r]);
        }
}

extern "C" void kernel_launch(void* const* d_in, const int* in_sizes, int n_in,
                              void* d_out, int out_size, void* d_ws, size_t ws_size,
                              hipStream_t stream) {
    const float* x      = (const float*)d_in[0];   // [2,2048,1024] fp32
    const float* W_attn = (const float*)d_in[1];   // [1024,3072]  fp32
    const float* W_proj = (const float*)d_in[2];   // [1024,1024]  fp32
    float* out = (float*)d_out;                    // [2,2048,1024] fp32

    u16* Wt_attn = (u16*)d_ws;                    // 3072*1024
    u16* Wt_proj = Wt_attn + 3072 * 1024;         // 1024*1024
    u16* xb      = Wt_proj + 1024 * 1024;         // 4096*1024 (reused as vt)
    u16* q       = xb + (size_t)MM * CC;
    u16* k       = q + (size_t)32 * 2048 * 64;
    u16* v       = k + (size_t)32 * 2048 * 64;
    u16* y       = v + (size_t)32 * 2048 * 64;
    u16* vt      = xb;                            // dead after gemm<0>

    cvt_x_k<<<dim3(MM * CC / 1024), 256, 0, stream>>>(x, xb);
    transpose_cvt_k<<<dim3(3072 / 64, 1024 / 64), dim3(64, 4), 0, stream>>>(
        W_attn, Wt_attn, 1024, 3072);
    transpose_cvt_k<<<dim3(1024 / 64, 1024 / 64), dim3(64, 4), 0, stream>>>(
        W_proj, Wt_proj, 1024, 1024);
    gemm_k<0><<<dim3(MM / 128, 3072 / 128), 256, 0, stream>>>(
        xb, Wt_attn, q, k, v, nullptr, 3072, 1024);
    transpose_v_k<<<dim3(TT / 64, BB * HH), dim3(64, 4), 0, stream>>>(v, vt);
    attn_k<<<dim3(256, 2), 512, 0, stream>>>(q, k, vt, y);
    gemm_k<1><<<dim3(MM / 128, 1024 / 128), 256, 0, stream>>>(
        y, Wt_proj, nullptr, nullptr, nullptr, out, 1024, 1024);
}

// Round 7
// 198.216 us; speedup vs baseline: 1.0936x; 1.0715x over previous
//
#include <hip/hip_runtime.h>

typedef unsigned short u16;
typedef __bf16 bf16x8 __attribute__((ext_vector_type(8)));
typedef float f32x4 __attribute__((ext_vector_type(4)));

#define BB 2
#define TT 2048
#define CC 1024
#define HH 16
#define DD 64
#define MM (BB*TT)   // 4096

__device__ __forceinline__ u16 f2b(float f) {
    union { float f; unsigned int i; } a; a.f = f;
    unsigned int u = a.i;
    unsigned int r = (u + 0x7FFFu + ((u >> 16) & 1u)) >> 16;
    return (u16)r;
}
__device__ __forceinline__ u16 f2b_fast(float f) {
    union { float f; unsigned int i; } a; a.f = f;
    return (u16)((a.i + 0x8000u) >> 16);
}

// async global -> LDS, 16B per lane (dest must be wave-uniform base + lane*16)
__device__ __forceinline__ void gld16(const u16* g, u16* l) {
    __builtin_amdgcn_global_load_lds(
        (const __attribute__((address_space(1))) unsigned int*)g,
        (__attribute__((address_space(3))) unsigned int*)l, 16, 0, 0);
}

// ---------------- fused preprocessing: one launch instead of three ----------------
// blocks [0,4096): fp32->bf16 cvt of x (4 float4/thread-block-row)
// blocks [4096,4864): W_attn [1024,3072] -> bf16 [3072,1024] transpose
// blocks [4864,5120): W_proj [1024,1024] -> bf16 [1024,1024] transpose
// Launch-gap accounting (R6 analysis): total - attn has been ~145 us across all
// rounds while kernel-work estimates sum to ~56 us -> ~10-12 us per dispatch of
// gap x 7 dispatches. Merging 3 prep kernels into 1 removes 2 gaps.
__global__ __launch_bounds__(256) void prep_k(const float* __restrict__ x,
                                              u16* __restrict__ xb,
                                              const float* __restrict__ Wa,
                                              u16* __restrict__ Wat,
                                              const float* __restrict__ Wp,
                                              u16* __restrict__ Wpt) {
    __shared__ u16 tile[64][65];
    const int b = blockIdx.x;
    const int tid = threadIdx.x;
    if (b < 4096) {                       // cvt_x role (block-uniform branch)
        int i = b * 256 + tid;
        float4 v = ((const float4*)x)[i];
        ushort4 o;
        o.x = f2b(v.x); o.y = f2b(v.y); o.z = f2b(v.z); o.w = f2b(v.w);
        ((ushort4*)xb)[i] = o;
        return;
    }
    const float* in; u16* out; int K, N, n0, k0;
    if (b < 4096 + 768) {                 // W_attn transpose role
        int bb = b - 4096;
        in = Wa; out = Wat; K = 1024; N = 3072;
        n0 = (bb % 48) * 64; k0 = (bb / 48) * 64;
    } else {                              // W_proj transpose role
        int bb = b - 4096 - 768;
        in = Wp; out = Wpt; K = 1024; N = 1024;
        n0 = (bb % 16) * 64; k0 = (bb / 16) * 64;
    }
    const int tx = tid & 63, ty = tid >> 6;
    for (int i = 0; i < 16; i++) {
        int row = ty + i * 4;
        tile[row][tx] = f2b(in[(size_t)(k0 + row) * N + n0 + tx]);
    }
    __syncthreads();
    for (int i = 0; i < 16; i++) {
        int row = ty + i * 4;
        out[(size_t)(n0 + row) * K + k0 + tx] = tile[tx][row];
    }
}

// ------ bf16 per-bh transpose: v[bh][T][D] -> vt[bh][D][T] ------
__global__ __launch_bounds__(256) void transpose_v_k(const u16* __restrict__ in,
                                                     u16* __restrict__ out) {
    __shared__ u16 tile[64][65];
    int t0 = blockIdx.x * 64, bh = blockIdx.y;
    const u16* src = in + (size_t)bh * TT * DD;
    u16* dst = out + (size_t)bh * DD * TT;
    int tx = threadIdx.x, ty = threadIdx.y;
    for (int i = 0; i < 16; i++) {
        int row = ty + i * 4;
        tile[row][tx] = src[(size_t)(t0 + row) * DD + tx];
    }
    __syncthreads();
    for (int i = 0; i < 16; i++) {
        int row = ty + i * 4;
        dst[(size_t)row * TT + t0 + tx] = tile[tx][row];
    }
}

// ---------------- GEMM: C[M,N] = A[M,K] * Bt[N,K]^T ----------------
// MODE 0 epilogue pre-scales q by 0.125*log2(e) for the attn log2-softmax.
template<int MODE>
__global__ __launch_bounds__(256) void gemm_k(const u16* __restrict__ A,
                                              const u16* __restrict__ Bt,
                                              u16* __restrict__ Cq,
                                              u16* __restrict__ Ck,
                                              u16* __restrict__ Cv,
                                              float* __restrict__ Cout,
                                              int N, int K) {
    __shared__ __attribute__((aligned(16))) u16 As[128 * 32];
    __shared__ __attribute__((aligned(16))) u16 Bs[128 * 32];
    const int tid  = threadIdx.x;
    const int lane = tid & 63, w = tid >> 6;
    const int wm = w >> 1, wn = w & 1;
    const int quad = lane >> 4, l16 = lane & 15;
    const int m0 = blockIdx.x * 128, n0 = blockIdx.y * 128;

    f32x4 acc[4][4];
    for (int mi = 0; mi < 4; mi++)
        for (int ni = 0; ni < 4; ni++)
            for (int e = 0; e < 4; e++) acc[mi][ni][e] = 0.f;

    for (int k0 = 0; k0 < K; k0 += 32) {
        for (int i = 0; i < 2; i++) {
            int c = tid + 256 * i;
            int row = c >> 2, col = (c & 3) * 8;
            const u16* srcA;
            if constexpr (MODE == 0) {
                srcA = A + (size_t)(m0 + row) * K + k0 + col;
            } else {
                int m = m0 + row;
                int b = m >> 11, t = m & 2047;
                int kk = k0 + col;
                int h = kk >> 6, d = kk & 63;
                srcA = A + ((size_t)(b * HH + h) * TT + t) * DD + d;
            }
            gld16(srcA, &As[c * 8]);
            gld16(Bt + (size_t)(n0 + row) * K + k0 + col, &Bs[c * 8]);
        }
        __syncthreads();
        bf16x8 af[4], bfm[4];
        for (int mi = 0; mi < 4; mi++)
            af[mi] = *(const bf16x8*)&As[(wm * 64 + mi * 16 + l16) * 32 + quad * 8];
        for (int ni = 0; ni < 4; ni++)
            bfm[ni] = *(const bf16x8*)&Bs[(wn * 64 + ni * 16 + l16) * 32 + quad * 8];
        for (int mi = 0; mi < 4; mi++)
            for (int ni = 0; ni < 4; ni++)
                acc[mi][ni] = __builtin_amdgcn_mfma_f32_16x16x32_bf16(
                    af[mi], bfm[ni], acc[mi][ni], 0, 0, 0);
        __syncthreads();
    }

    const float SCQ = 0.125f * 1.44269504f;
    for (int mi = 0; mi < 4; mi++)
        for (int ni = 0; ni < 4; ni++)
            for (int r = 0; r < 4; r++) {
                int row = m0 + wm * 64 + mi * 16 + quad * 4 + r;
                int col = n0 + wn * 64 + ni * 16 + l16;
                if constexpr (MODE == 0) {
                    int which = col >> 10;
                    int h = (col >> 6) & 15, d = col & 63;
                    int b = row >> 11, t = row & 2047;
                    size_t off = ((size_t)(b * HH + h) * TT + t) * DD + d;
                    float val = acc[mi][ni][r];
                    if (which == 0) val *= SCQ;
                    (which == 0 ? Cq : which == 1 ? Ck : Cv)[off] = f2b(val);
                } else {
                    Cout[(size_t)row * N + col] = acc[mi][ni][r];
                }
            }
}

// ---------------- flash attention v8 (reverted best: 58.0 us measured) ----------------
// Grid (bh=32, y=32); XCD = bh%8 keeps each head's K/V in one XCD L2.
// K AND V double-buffered, ONE __syncthreads per pass; K[jk+1] and V[jk+1]
// staged immediately after it into the buffers last read in pass jk-1.
// XOR swizzle slot^=(row&7) on global source + ds_read (both-sides, LDS linear
// for the DMA). LDS: 32K (K dbuf) + 32K (V dbuf) + 16K (Ps) = 80 KB.
// __launch_bounds__(256,2): 256-VGPR budget (min-waves>=3 forces 64 VGPR and
// spills ~28MB to scratch -- R1/R5 lesson). Measured: VGPR 88, no spill.
// R5/R6 lesson: 512-thread restructure (waves-share-staging) regressed to
// 66-76 us; this 256-thread config is the local optimum of this structure.
__global__ __launch_bounds__(256, 2) void attn_k(const u16* __restrict__ Q,
                                                 const u16* __restrict__ Kb,
                                                 const u16* __restrict__ Vtg,
                                                 u16* __restrict__ Y) {
    __shared__ __attribute__((aligned(16))) u16 Ks[2][128 * 64];  // 32 KB
    __shared__ __attribute__((aligned(16))) u16 Vs[2][64 * 128];  // 32 KB
    __shared__ __attribute__((aligned(16))) u16 Ps[4][16 * 128];  // 16 KB
    const int tid  = threadIdx.x;
    const int lane = tid & 63, w = tid >> 6;
    const int quad = lane >> 4, l16 = lane & 15;
    const int bh = blockIdx.x;                 // 0..31 -> XCD = bh%8
    const int y  = blockIdx.y;                 // 0..31
    // work table balances causal load: work = nkt = (sb>>1)+1
    const int rowi = (y >> 1) & 3, coli = y >> 3;
    const int basew = ((coli & 1) ? 9 : 16) - ((coli >> 1) << 3);
    const int work = basew + ((coli & 1) ? rowi : -rowi);
    const int sb = 2 * (work - 1) + (y & 1);
    const int nkt = work;
    const size_t base  = (size_t)bh * TT * DD;
    const size_t baseV = (size_t)bh * DD * TT;

    // per-lane staging offsets: 4 rounds x 256 lanes cover 1024 16B-slots/tile.
    // content swizzle: LDS slot s of row holds global col-group s^(row&7).
    int ksidx[4], koff[4], voff[4];
    for (int r = 0; r < 4; r++) {
        int sidx = r * 256 + tid;
        ksidx[r] = sidx;
        int kr = sidx >> 3, ksl = sidx & 7;
        koff[r] = kr * 64 + ((ksl ^ (kr & 7)) << 3);
        int vr = sidx >> 4, vsl = sidx & 15;
        voff[r] = vr * TT + ((vsl ^ (vr & 7)) << 3);
    }
    const u16* kg = Kb + base;      // + jk*8192 + koff[r]
    const u16* vg = Vtg + baseV;    // + jk*128  + voff[r]

    // prologue: stage tile 0
    for (int r = 0; r < 4; r++) gld16(kg + koff[r], &Ks[0][ksidx[r] * 8]);
    for (int r = 0; r < 4; r++) gld16(vg + voff[r], &Vs[0][ksidx[r] * 8]);

    // Q fragments (A-layout, pre-scaled by 0.125*log2e in gemm0 epilogue)
    bf16x8 qf[2];
    for (int kk = 0; kk < 2; kk++)
        qf[kk] = *(const bf16x8*)(Q + base +
            (size_t)(sb * 64 + w * 16 + l16) * DD + kk * 32 + quad * 8);

    // ds_read swizzled slot offsets (u16 elements)
    const int swx = (l16 & 7);
    const int swk0 = ((quad ^ swx) << 3);
    const int swk1 = (((4 + quad) ^ swx) << 3);

    float mst[4], lst[4];
    f32x4 oacc[4];
    for (int r = 0; r < 4; r++) { mst[r] = -1e30f; lst[r] = 0.f; }
    for (int nd = 0; nd < 4; nd++)
        for (int e = 0; e < 4; e++) oacc[nd][e] = 0.f;

    for (int jk = 0; jk < nkt; jk++) {
        const int cb = jk & 1;
        __syncthreads();   // ONE barrier/pass: stage(jk) visible; buffers cb^1 free

        // stage next K+V tiles (full pass of cover before next barrier's drain)
        if (jk + 1 < nkt) {
            const u16* kn = kg + (size_t)(jk + 1) * (128 * DD);
            const u16* vn = vg + (size_t)(jk + 1) * 128;
            for (int r = 0; r < 4; r++)
                gld16(kn + koff[r], &Ks[cb ^ 1][ksidx[r] * 8]);
            for (int r = 0; r < 4; r++)
                gld16(vn + voff[r], &Vs[cb ^ 1][ksidx[r] * 8]);
        }

        // ---- S = Q K^T from LDS (swizzled ds_read_b128) ----
        f32x4 s[8];
        for (int ni = 0; ni < 8; ni++)
            for (int e = 0; e < 4; e++) s[ni][e] = 0.f;
        {
            bf16x8 kfa[8];
            for (int ni = 0; ni < 8; ni++)
                kfa[ni] = *(const bf16x8*)&Ks[cb][(ni * 16 + l16) * 64 + swk0];
            for (int ni = 0; ni < 8; ni++)
                s[ni] = __builtin_amdgcn_mfma_f32_16x16x32_bf16(
                    qf[0], kfa[ni], s[ni], 0, 0, 0);
        }
        {
            bf16x8 kfa[8];
            for (int ni = 0; ni < 8; ni++)
                kfa[ni] = *(const bf16x8*)&Ks[cb][(ni * 16 + l16) * 64 + swk1];
            for (int ni = 0; ni < 8; ni++)
                s[ni] = __builtin_amdgcn_mfma_f32_16x16x32_bf16(
                    qf[1], kfa[ni], s[ni], 0, 0, 0);
        }

        // ---- online softmax (log2 domain) + Ps write ----
        if (jk == (sb >> 1)) {                 // diagonal tile: causal mask
            int row0 = sb * 64 + w * 16 + quad * 4;
            int col0 = jk * 128 + l16;
            for (int ni = 0; ni < 8; ni++)
                for (int r = 0; r < 4; r++)
                    if (col0 + ni * 16 > row0 + r) s[ni][r] = -1e30f;
        }
        float alpha[4];
        for (int r = 0; r < 4; r++) {
            float mx = s[0][r];
            for (int ni = 1; ni < 8; ni++) mx = fmaxf(mx, s[ni][r]);
            for (int off = 8; off >= 1; off >>= 1)
                mx = fmaxf(mx, __shfl_xor(mx, off));
            float mn = fmaxf(mst[r], mx);
            alpha[r] = __builtin_amdgcn_exp2f(mst[r] - mn);
            mst[r] = mn;
        }
        float rs[4] = {0.f, 0.f, 0.f, 0.f};
        for (int ni = 0; ni < 8; ni++)
            for (int r = 0; r < 4; r++) {
                float pv = __builtin_amdgcn_exp2f(s[ni][r] - mst[r]);
                rs[r] += pv;
                int row = quad * 4 + r;
                int cg  = ni * 2 + (l16 >> 3);
                Ps[w][row * 128 + ((cg ^ row) << 3) + (l16 & 7)] = f2b_fast(pv);
            }
        for (int r = 0; r < 4; r++) {
            float sm = rs[r];
            for (int off = 8; off >= 1; off >>= 1)
                sm += __shfl_xor(sm, off);
            lst[r] = lst[r] * alpha[r] + sm;
            for (int nd = 0; nd < 4; nd++) oacc[nd][r] *= alpha[r];
        }

        // ---- O += P V from LDS ----
        for (int kk = 0; kk < 4; kk++) {
            const int swv = (((kk * 4 + quad) ^ swx) << 3);
            bf16x8 vfa[4];
            for (int nd = 0; nd < 4; nd++)
                vfa[nd] = *(const bf16x8*)&Vs[cb][(nd * 16 + l16) * 128 + swv];
            bf16x8 pf = *(const bf16x8*)&Ps[w][l16 * 128 +
                (((kk * 4 + quad) ^ l16) << 3)];
            for (int nd = 0; nd < 4; nd++)
                oacc[nd] = __builtin_amdgcn_mfma_f32_16x16x32_bf16(
                    pf, vfa[nd], oacc[nd], 0, 0, 0);
        }
    }

    for (int nd = 0; nd < 4; nd++)
        for (int r = 0; r < 4; r++) {
            int row = sb * 64 + w * 16 + quad * 4 + r;
            int col = nd * 16 + l16;
            Y[base + (size_t)row * DD + col] = f2b(oacc[nd][r] / lst[r]);
        }
}

extern "C" void kernel_launch(void* const* d_in, const int* in_sizes, int n_in,
                              void* d_out, int out_size, void* d_ws, size_t ws_size,
                              hipStream_t stream) {
    const float* x      = (const float*)d_in[0];   // [2,2048,1024] fp32
    const float* W_attn = (const float*)d_in[1];   // [1024,3072]  fp32
    const float* W_proj = (const float*)d_in[2];   // [1024,1024]  fp32
    float* out = (float*)d_out;                    // [2,2048,1024] fp32

    u16* Wt_attn = (u16*)d_ws;                    // 3072*1024
    u16* Wt_proj = Wt_attn + 3072 * 1024;         // 1024*1024
    u16* xb      = Wt_proj + 1024 * 1024;         // 4096*1024 (reused as vt)
    u16* q       = xb + (size_t)MM * CC;
    u16* k       = q + (size_t)32 * 2048 * 64;
    u16* v       = k + (size_t)32 * 2048 * 64;
    u16* y       = v + (size_t)32 * 2048 * 64;
    u16* vt      = xb;                            // dead after gemm<0>

    // 5 launches (was 7): prep merges cvt_x + both weight transposes.
    prep_k<<<dim3(4096 + 768 + 256), 256, 0, stream>>>(
        x, xb, W_attn, Wt_attn, W_proj, Wt_proj);
    gemm_k<0><<<dim3(MM / 128, 3072 / 128), 256, 0, stream>>>(
        xb, Wt_attn, q, k, v, nullptr, 3072, 1024);
    transpose_v_k<<<dim3(TT / 64, BB * HH), dim3(64, 4), 0, stream>>>(v, vt);
    attn_k<<<dim3(32, 32), 256, 0, stream>>>(q, k, vt, y);
    gemm_k<1><<<dim3(MM / 128, 1024 / 128), 256, 0, stream>>>(
        y, Wt_proj, nullptr, nullptr, nullptr, out, 1024, 1024);
}

// Round 8
// 194.123 us; speedup vs baseline: 1.1167x; 1.0211x over previous
//
#include <hip/hip_runtime.h>

typedef unsigned short u16;
typedef __bf16 bf16x8 __attribute__((ext_vector_type(8)));
typedef float f32x4 __attribute__((ext_vector_type(4)));

#define BB 2
#define TT 2048
#define CC 1024
#define HH 16
#define DD 64
#define MM (BB*TT)   // 4096

__device__ __forceinline__ u16 f2b(float f) {
    union { float f; unsigned int i; } a; a.f = f;
    unsigned int u = a.i;
    unsigned int r = (u + 0x7FFFu + ((u >> 16) & 1u)) >> 16;
    return (u16)r;
}
__device__ __forceinline__ u16 f2b_fast(float f) {
    union { float f; unsigned int i; } a; a.f = f;
    return (u16)((a.i + 0x8000u) >> 16);
}

// async global -> LDS, 16B per lane (dest must be wave-uniform base + lane*16)
__device__ __forceinline__ void gld16(const u16* g, u16* l) {
    __builtin_amdgcn_global_load_lds(
        (const __attribute__((address_space(1))) unsigned int*)g,
        (__attribute__((address_space(3))) unsigned int*)l, 16, 0, 0);
}

// ---------------- fused preprocessing: one launch instead of three ----------------
__global__ __launch_bounds__(256) void prep_k(const float* __restrict__ x,
                                              u16* __restrict__ xb,
                                              const float* __restrict__ Wa,
                                              u16* __restrict__ Wat,
                                              const float* __restrict__ Wp,
                                              u16* __restrict__ Wpt) {
    __shared__ u16 tile[64][65];
    const int b = blockIdx.x;
    const int tid = threadIdx.x;
    if (b < 4096) {                       // cvt_x role (block-uniform branch)
        int i = b * 256 + tid;
        float4 v = ((const float4*)x)[i];
        ushort4 o;
        o.x = f2b(v.x); o.y = f2b(v.y); o.z = f2b(v.z); o.w = f2b(v.w);
        ((ushort4*)xb)[i] = o;
        return;
    }
    const float* in; u16* out; int K, N, n0, k0;
    if (b < 4096 + 768) {                 // W_attn transpose role
        int bb = b - 4096;
        in = Wa; out = Wat; K = 1024; N = 3072;
        n0 = (bb % 48) * 64; k0 = (bb / 48) * 64;
    } else {                              // W_proj transpose role
        int bb = b - 4096 - 768;
        in = Wp; out = Wpt; K = 1024; N = 1024;
        n0 = (bb % 16) * 64; k0 = (bb / 16) * 64;
    }
    const int tx = tid & 63, ty = tid >> 6;
    for (int i = 0; i < 16; i++) {
        int row = ty + i * 4;
        tile[row][tx] = f2b(in[(size_t)(k0 + row) * N + n0 + tx]);
    }
    __syncthreads();
    for (int i = 0; i < 16; i++) {
        int row = ty + i * 4;
        out[(size_t)(n0 + row) * K + k0 + tx] = tile[tx][row];
    }
}

// ------ bf16 per-bh transpose: v[bh][T][D] -> vt[bh][D][T] ------
__global__ __launch_bounds__(256) void transpose_v_k(const u16* __restrict__ in,
                                                     u16* __restrict__ out) {
    __shared__ u16 tile[64][65];
    int t0 = blockIdx.x * 64, bh = blockIdx.y;
    const u16* src = in + (size_t)bh * TT * DD;
    u16* dst = out + (size_t)bh * DD * TT;
    int tx = threadIdx.x, ty = threadIdx.y;
    for (int i = 0; i < 16; i++) {
        int row = ty + i * 4;
        tile[row][tx] = src[(size_t)(t0 + row) * DD + tx];
    }
    __syncthreads();
    for (int i = 0; i < 16; i++) {
        int row = ty + i * 4;
        dst[(size_t)row * TT + t0 + tx] = tile[tx][row];
    }
}

// ---------------- GEMM v2: K-prefetch double-buffer + XCD swizzle ----------------
// R7 accounting: gemm0+gemm1 ~75-85 us for 34 GFLOP -- the old 2-barrier loop
// (gld16 -> syncthreads drain with ZERO cover -> compute -> syncthreads) exposes
// full staging latency on all 32 K-steps; gemm1 runs at exactly 1 block/CU so
// nothing hides it. Fix = the attn-v8 schedule: ONE barrier per K-step, stage
// k+1 into the alternate buffer right after it, compute current. LDS 32 KB.
// 1-D grid, bijective XCD swizzle (nwg%8==0): contiguous chunk per XCD,
// n-major within chunk -> A-panel stays in XCD-local L2.
// MODE 0 epilogue pre-scales q by 0.125*log2(e) for the attn log2-softmax.
template<int MODE>
__global__ __launch_bounds__(256) void gemm_k(const u16* __restrict__ A,
                                              const u16* __restrict__ Bt,
                                              u16* __restrict__ Cq,
                                              u16* __restrict__ Ck,
                                              u16* __restrict__ Cv,
                                              float* __restrict__ Cout,
                                              int N, int K) {
    __shared__ __attribute__((aligned(16))) u16 As[2][128 * 32];
    __shared__ __attribute__((aligned(16))) u16 Bs[2][128 * 32];
    const int tid  = threadIdx.x;
    const int lane = tid & 63, w = tid >> 6;
    const int wm = w >> 1, wn = w & 1;
    const int quad = lane >> 4, l16 = lane & 15;

    // XCD-aware bijective swizzle (gridDim.x % 8 == 0)
    const int nwg = gridDim.x, lin = blockIdx.x;
    const int cpx = nwg >> 3;
    const int sw  = (lin & 7) * cpx + (lin >> 3);
    const int ncols = N >> 7;
    const int m0 = (sw / ncols) * 128, n0 = (sw % ncols) * 128;

    f32x4 acc[4][4];
    for (int mi = 0; mi < 4; mi++)
        for (int ni = 0; ni < 4; ni++)
            for (int e = 0; e < 4; e++) acc[mi][ni][e] = 0.f;

#define GSTAGE(BUF, K0)                                                   \
    for (int i = 0; i < 2; i++) {                                         \
        int c = tid + 256 * i;                                            \
        int row = c >> 2, col = (c & 3) * 8;                              \
        const u16* srcA;                                                  \
        if constexpr (MODE == 0) {                                        \
            srcA = A + (size_t)(m0 + row) * K + (K0) + col;               \
        } else {                                                          \
            int m = m0 + row;                                             \
            int b = m >> 11, t = m & 2047;                                \
            int kk = (K0) + col;                                          \
            int h = kk >> 6, d = kk & 63;                                 \
            srcA = A + ((size_t)(b * HH + h) * TT + t) * DD + d;          \
        }                                                                 \
        gld16(srcA, &As[BUF][c * 8]);                                     \
        gld16(Bt + (size_t)(n0 + row) * K + (K0) + col, &Bs[BUF][c * 8]); \
    }

    GSTAGE(0, 0);                         // prologue: stage K-step 0
    const int nk = K >> 5;
    for (int jk = 0; jk < nk; jk++) {
        const int cb = jk & 1;
        __syncthreads();                  // stage(jk) visible; buf cb^1 free
        if (jk + 1 < nk) { GSTAGE(cb ^ 1, (jk + 1) * 32); }
        bf16x8 af[4], bfm[4];
        for (int mi = 0; mi < 4; mi++)
            af[mi] = *(const bf16x8*)&As[cb][(wm * 64 + mi * 16 + l16) * 32 + quad * 8];
        for (int ni = 0; ni < 4; ni++)
            bfm[ni] = *(const bf16x8*)&Bs[cb][(wn * 64 + ni * 16 + l16) * 32 + quad * 8];
        for (int mi = 0; mi < 4; mi++)
            for (int ni = 0; ni < 4; ni++)
                acc[mi][ni] = __builtin_amdgcn_mfma_f32_16x16x32_bf16(
                    af[mi], bfm[ni], acc[mi][ni], 0, 0, 0);
    }
#undef GSTAGE

    const float SCQ = 0.125f * 1.44269504f;
    for (int mi = 0; mi < 4; mi++)
        for (int ni = 0; ni < 4; ni++)
            for (int r = 0; r < 4; r++) {
                int row = m0 + wm * 64 + mi * 16 + quad * 4 + r;
                int col = n0 + wn * 64 + ni * 16 + l16;
                if constexpr (MODE == 0) {
                    int which = col >> 10;
                    int h = (col >> 6) & 15, d = col & 63;
                    int b = row >> 11, t = row & 2047;
                    size_t off = ((size_t)(b * HH + h) * TT + t) * DD + d;
                    float val = acc[mi][ni][r];
                    if (which == 0) val *= SCQ;
                    (which == 0 ? Cq : which == 1 ? Ck : Cv)[off] = f2b(val);
                } else {
                    Cout[(size_t)row * N + col] = acc[mi][ni][r];
                }
            }
}

// ---------------- flash attention v8 (best measured; session noise 58-67 us) ----------------
// Grid (bh=32, y=32); XCD = bh%8 keeps each head's K/V in one XCD L2.
// K AND V double-buffered, ONE __syncthreads per pass; K[jk+1] and V[jk+1]
// staged immediately after it into the buffers last read in pass jk-1.
// XOR swizzle slot^=(row&7) on global source + ds_read (both-sides, LDS linear
// for the DMA). LDS: 32K (K dbuf) + 32K (V dbuf) + 16K (Ps) = 80 KB.
// __launch_bounds__(256,2): min-waves>=3 forces 64 VGPR + ~28MB scratch spill
// (R1/R5 lesson). Measured: VGPR 88, no spill.
__global__ __launch_bounds__(256, 2) void attn_k(const u16* __restrict__ Q,
                                                 const u16* __restrict__ Kb,
                                                 const u16* __restrict__ Vtg,
                                                 u16* __restrict__ Y) {
    __shared__ __attribute__((aligned(16))) u16 Ks[2][128 * 64];  // 32 KB
    __shared__ __attribute__((aligned(16))) u16 Vs[2][64 * 128];  // 32 KB
    __shared__ __attribute__((aligned(16))) u16 Ps[4][16 * 128];  // 16 KB
    const int tid  = threadIdx.x;
    const int lane = tid & 63, w = tid >> 6;
    const int quad = lane >> 4, l16 = lane & 15;
    const int bh = blockIdx.x;                 // 0..31 -> XCD = bh%8
    const int y  = blockIdx.y;                 // 0..31
    // work table balances causal load: work = nkt = (sb>>1)+1
    const int rowi = (y >> 1) & 3, coli = y >> 3;
    const int basew = ((coli & 1) ? 9 : 16) - ((coli >> 1) << 3);
    const int work = basew + ((coli & 1) ? rowi : -rowi);
    const int sb = 2 * (work - 1) + (y & 1);
    const int nkt = work;
    const size_t base  = (size_t)bh * TT * DD;
    const size_t baseV = (size_t)bh * DD * TT;

    // per-lane staging offsets: 4 rounds x 256 lanes cover 1024 16B-slots/tile.
    // content swizzle: LDS slot s of row holds global col-group s^(row&7).
    int ksidx[4], koff[4], voff[4];
    for (int r = 0; r < 4; r++) {
        int sidx = r * 256 + tid;
        ksidx[r] = sidx;
        int kr = sidx >> 3, ksl = sidx & 7;
        koff[r] = kr * 64 + ((ksl ^ (kr & 7)) << 3);
        int vr = sidx >> 4, vsl = sidx & 15;
        voff[r] = vr * TT + ((vsl ^ (vr & 7)) << 3);
    }
    const u16* kg = Kb + base;      // + jk*8192 + koff[r]
    const u16* vg = Vtg + baseV;    // + jk*128  + voff[r]

    // prologue: stage tile 0
    for (int r = 0; r < 4; r++) gld16(kg + koff[r], &Ks[0][ksidx[r] * 8]);
    for (int r = 0; r < 4; r++) gld16(vg + voff[r], &Vs[0][ksidx[r] * 8]);

    // Q fragments (A-layout, pre-scaled by 0.125*log2e in gemm0 epilogue)
    bf16x8 qf[2];
    for (int kk = 0; kk < 2; kk++)
        qf[kk] = *(const bf16x8*)(Q + base +
            (size_t)(sb * 64 + w * 16 + l16) * DD + kk * 32 + quad * 8);

    // ds_read swizzled slot offsets (u16 elements)
    const int swx = (l16 & 7);
    const int swk0 = ((quad ^ swx) << 3);
    const int swk1 = (((4 + quad) ^ swx) << 3);

    float mst[4], lst[4];
    f32x4 oacc[4];
    for (int r = 0; r < 4; r++) { mst[r] = -1e30f; lst[r] = 0.f; }
    for (int nd = 0; nd < 4; nd++)
        for (int e = 0; e < 4; e++) oacc[nd][e] = 0.f;

    for (int jk = 0; jk < nkt; jk++) {
        const int cb = jk & 1;
        __syncthreads();   // ONE barrier/pass: stage(jk) visible; buffers cb^1 free

        // stage next K+V tiles (full pass of cover before next barrier's drain)
        if (jk + 1 < nkt) {
            const u16* kn = kg + (size_t)(jk + 1) * (128 * DD);
            const u16* vn = vg + (size_t)(jk + 1) * 128;
            for (int r = 0; r < 4; r++)
                gld16(kn + koff[r], &Ks[cb ^ 1][ksidx[r] * 8]);
            for (int r = 0; r < 4; r++)
                gld16(vn + voff[r], &Vs[cb ^ 1][ksidx[r] * 8]);
        }

        // ---- S = Q K^T from LDS (swizzled ds_read_b128) ----
        f32x4 s[8];
        for (int ni = 0; ni < 8; ni++)
            for (int e = 0; e < 4; e++) s[ni][e] = 0.f;
        {
            bf16x8 kfa[8];
            for (int ni = 0; ni < 8; ni++)
                kfa[ni] = *(const bf16x8*)&Ks[cb][(ni * 16 + l16) * 64 + swk0];
            for (int ni = 0; ni < 8; ni++)
                s[ni] = __builtin_amdgcn_mfma_f32_16x16x32_bf16(
                    qf[0], kfa[ni], s[ni], 0, 0, 0);
        }
        {
            bf16x8 kfa[8];
            for (int ni = 0; ni < 8; ni++)
                kfa[ni] = *(const bf16x8*)&Ks[cb][(ni * 16 + l16) * 64 + swk1];
            for (int ni = 0; ni < 8; ni++)
                s[ni] = __builtin_amdgcn_mfma_f32_16x16x32_bf16(
                    qf[1], kfa[ni], s[ni], 0, 0, 0);
        }

        // ---- online softmax (log2 domain) + Ps write ----
        if (jk == (sb >> 1)) {                 // diagonal tile: causal mask
            int row0 = sb * 64 + w * 16 + quad * 4;
            int col0 = jk * 128 + l16;
            for (int ni = 0; ni < 8; ni++)
                for (int r = 0; r < 4; r++)
                    if (col0 + ni * 16 > row0 + r) s[ni][r] = -1e30f;
        }
        float alpha[4];
        for (int r = 0; r < 4; r++) {
            float mx = s[0][r];
            for (int ni = 1; ni < 8; ni++) mx = fmaxf(mx, s[ni][r]);
            for (int off = 8; off >= 1; off >>= 1)
                mx = fmaxf(mx, __shfl_xor(mx, off));
            float mn = fmaxf(mst[r], mx);
            alpha[r] = __builtin_amdgcn_exp2f(mst[r] - mn);
            mst[r] = mn;
        }
        float rs[4] = {0.f, 0.f, 0.f, 0.f};
        for (int ni = 0; ni < 8; ni++)
            for (int r = 0; r < 4; r++) {
                float pv = __builtin_amdgcn_exp2f(s[ni][r] - mst[r]);
                rs[r] += pv;
                int row = quad * 4 + r;
                int cg  = ni * 2 + (l16 >> 3);
                Ps[w][row * 128 + ((cg ^ row) << 3) + (l16 & 7)] = f2b_fast(pv);
            }
        for (int r = 0; r < 4; r++) {
            float sm = rs[r];
            for (int off = 8; off >= 1; off >>= 1)
                sm += __shfl_xor(sm, off);
            lst[r] = lst[r] * alpha[r] + sm;
            for (int nd = 0; nd < 4; nd++) oacc[nd][r] *= alpha[r];
        }

        // ---- O += P V from LDS ----
        for (int kk = 0; kk < 4; kk++) {
            const int swv = (((kk * 4 + quad) ^ swx) << 3);
            bf16x8 vfa[4];
            for (int nd = 0; nd < 4; nd++)
                vfa[nd] = *(const bf16x8*)&Vs[cb][(nd * 16 + l16) * 128 + swv];
            bf16x8 pf = *(const bf16x8*)&Ps[w][l16 * 128 +
                (((kk * 4 + quad) ^ l16) << 3)];
            for (int nd = 0; nd < 4; nd++)
                oacc[nd] = __builtin_amdgcn_mfma_f32_16x16x32_bf16(
                    pf, vfa[nd], oacc[nd], 0, 0, 0);
        }
    }

    for (int nd = 0; nd < 4; nd++)
        for (int r = 0; r < 4; r++) {
            int row = sb * 64 + w * 16 + quad * 4 + r;
            int col = nd * 16 + l16;
            Y[base + (size_t)row * DD + col] = f2b(oacc[nd][r] / lst[r]);
        }
}

extern "C" void kernel_launch(void* const* d_in, const int* in_sizes, int n_in,
                              void* d_out, int out_size, void* d_ws, size_t ws_size,
                              hipStream_t stream) {
    const float* x      = (const float*)d_in[0];   // [2,2048,1024] fp32
    const float* W_attn = (const float*)d_in[1];   // [1024,3072]  fp32
    const float* W_proj = (const float*)d_in[2];   // [1024,1024]  fp32
    float* out = (float*)d_out;                    // [2,2048,1024] fp32

    u16* Wt_attn = (u16*)d_ws;                    // 3072*1024
    u16* Wt_proj = Wt_attn + 3072 * 1024;         // 1024*1024
    u16* xb      = Wt_proj + 1024 * 1024;         // 4096*1024 (reused as vt)
    u16* q       = xb + (size_t)MM * CC;
    u16* k       = q + (size_t)32 * 2048 * 64;
    u16* v       = k + (size_t)32 * 2048 * 64;
    u16* y       = v + (size_t)32 * 2048 * 64;
    u16* vt      = xb;                            // dead after gemm<0>

    // 5 launches: prep (fused) -> gemm0 -> transpose_v -> attn -> gemm1
    prep_k<<<dim3(4096 + 768 + 256), 256, 0, stream>>>(
        x, xb, W_attn, Wt_attn, W_proj, Wt_proj);
    gemm_k<0><<<dim3((MM / 128) * (3072 / 128)), 256, 0, stream>>>(
        xb, Wt_attn, q, k, v, nullptr, 3072, 1024);
    transpose_v_k<<<dim3(TT / 64, BB * HH), dim3(64, 4), 0, stream>>>(v, vt);
    attn_k<<<dim3(32, 32), 256, 0, stream>>>(q, k, vt, y);
    gemm_k<1><<<dim3((MM / 128) * (1024 / 128)), 256, 0, stream>>>(
        y, Wt_proj, nullptr, nullptr, nullptr, out, 1024, 1024);
}

// Round 9
// 181.057 us; speedup vs baseline: 1.1972x; 1.0722x over previous
//
#include <hip/hip_runtime.h>

typedef unsigned short u16;
typedef __bf16 bf16x8 __attribute__((ext_vector_type(8)));
typedef float f32x4 __attribute__((ext_vector_type(4)));

#define BB 2
#define TT 2048
#define CC 1024
#define HH 16
#define DD 64
#define MM (BB*TT)   // 4096

__device__ __forceinline__ u16 f2b(float f) {
    union { float f; unsigned int i; } a; a.f = f;
    unsigned int u = a.i;
    unsigned int r = (u + 0x7FFFu + ((u >> 16) & 1u)) >> 16;
    return (u16)r;
}
__device__ __forceinline__ u16 f2b_fast(float f) {
    union { float f; unsigned int i; } a; a.f = f;
    return (u16)((a.i + 0x8000u) >> 16);
}

// async global -> LDS, 16B per lane (dest must be wave-uniform base + lane*16)
__device__ __forceinline__ void gld16(const u16* g, u16* l) {
    __builtin_amdgcn_global_load_lds(
        (const __attribute__((address_space(1))) unsigned int*)g,
        (__attribute__((address_space(3))) unsigned int*)l, 16, 0, 0);
}

// ---------------- fused preprocessing: one launch instead of three ----------------
__global__ __launch_bounds__(256) void prep_k(const float* __restrict__ x,
                                              u16* __restrict__ xb,
                                              const float* __restrict__ Wa,
                                              u16* __restrict__ Wat,
                                              const float* __restrict__ Wp,
                                              u16* __restrict__ Wpt) {
    __shared__ u16 tile[64][65];
    const int b = blockIdx.x;
    const int tid = threadIdx.x;
    if (b < 4096) {                       // cvt_x role (block-uniform branch)
        int i = b * 256 + tid;
        float4 v = ((const float4*)x)[i];
        ushort4 o;
        o.x = f2b(v.x); o.y = f2b(v.y); o.z = f2b(v.z); o.w = f2b(v.w);
        ((ushort4*)xb)[i] = o;
        return;
    }
    const float* in; u16* out; int K, N, n0, k0;
    if (b < 4096 + 768) {                 // W_attn transpose role
        int bb = b - 4096;
        in = Wa; out = Wat; K = 1024; N = 3072;
        n0 = (bb % 48) * 64; k0 = (bb / 48) * 64;
    } else {                              // W_proj transpose role
        int bb = b - 4096 - 768;
        in = Wp; out = Wpt; K = 1024; N = 1024;
        n0 = (bb % 16) * 64; k0 = (bb / 16) * 64;
    }
    const int tx = tid & 63, ty = tid >> 6;
    for (int i = 0; i < 16; i++) {
        int row = ty + i * 4;
        tile[row][tx] = f2b(in[(size_t)(k0 + row) * N + n0 + tx]);
    }
    __syncthreads();
    for (int i = 0; i < 16; i++) {
        int row = ty + i * 4;
        out[(size_t)(n0 + row) * K + k0 + tx] = tile[tx][row];
    }
}

// ---------------- GEMM v3: dbuf + XCD swizzle + fused vt-transpose epilogue ----------------
// MODE 0: C = [q|k|v], 128x128 tile. q/k written [bh][T][D] (q pre-scaled by
//   0.125*log2e). v-blocks (n0>>10==2, block-uniform) route acc through an
//   in-LDS [128c][136t] transpose tile (unioned with the dead As/Bs staging
//   space) and store vt[bh][D][T] 16B-coalesced along T -- this deletes the
//   standalone transpose_v kernel AND the v buffer.
// MODE 1: Cout fp32, 128x64 tile -> 512 blocks = 2 blocks/CU (was 256 = 1/CU,
//   zero co-residency -- every stall serial).
// Both: ONE barrier per K-step, K-step k+1 staged right after it (attn-v8
// schedule); bijective XCD swizzle, n-major within chunk (A-panel L2 reuse).
template<int MODE>
__global__ __launch_bounds__(256) void gemm_k(const u16* __restrict__ A,
                                              const u16* __restrict__ Bt,
                                              u16* __restrict__ Cq,
                                              u16* __restrict__ Ck,
                                              u16* __restrict__ Cv,
                                              float* __restrict__ Cout,
                                              int N, int K) {
    constexpr int BN   = (MODE == 0) ? 128 : 64;
    constexpr int NF   = (MODE == 0) ? 4 : 2;
    constexpr int BSU  = BN * 32;                       // Bs u16 per buffer
    constexpr int LDSZ = (MODE == 0) ? (128 * 136) : (2 * 4096 + 2 * BSU);
    __shared__ __attribute__((aligned(16))) u16 smem[LDSZ];
#define AsP(B) (smem + (B) * 4096)
#define BsP(B) (smem + 8192 + (B) * BSU)

    const int tid  = threadIdx.x;
    const int lane = tid & 63, w = tid >> 6;
    const int wm = w >> 1, wn = w & 1;
    const int quad = lane >> 4, l16 = lane & 15;

    // XCD-aware bijective swizzle (gridDim.x % 8 == 0)
    const int nwg = gridDim.x, lin = blockIdx.x;
    const int cpx = nwg >> 3;
    const int sw  = (lin & 7) * cpx + (lin >> 3);
    const int ncols = N / BN;
    const int m0 = (sw / ncols) * 128, n0 = (sw % ncols) * BN;

    f32x4 acc[4][NF];
    for (int mi = 0; mi < 4; mi++)
        for (int ni = 0; ni < NF; ni++)
            for (int e = 0; e < 4; e++) acc[mi][ni][e] = 0.f;

#define GSTAGE(BUF, K0) do {                                                  \
    for (int i = 0; i < 2; i++) {                                             \
        int c = tid + 256 * i;                                                \
        int row = c >> 2, col = (c & 3) * 8;                                  \
        const u16* srcA;                                                      \
        if constexpr (MODE == 0) {                                            \
            srcA = A + (size_t)(m0 + row) * K + (K0) + col;                   \
        } else {                                                              \
            int m = m0 + row;                                                 \
            int b = m >> 11, t = m & 2047;                                    \
            int kk = (K0) + col;                                              \
            int h = kk >> 6, d = kk & 63;                                     \
            srcA = A + ((size_t)(b * HH + h) * TT + t) * DD + d;              \
        }                                                                     \
        gld16(srcA, AsP(BUF) + c * 8);                                        \
    }                                                                         \
    if constexpr (MODE == 0) {                                                \
        for (int i = 0; i < 2; i++) {                                         \
            int c = tid + 256 * i;                                            \
            int row = c >> 2, col = (c & 3) * 8;                              \
            gld16(Bt + (size_t)(n0 + row) * K + (K0) + col, BsP(BUF) + c * 8);\
        }                                                                     \
    } else {                                                                  \
        int row = tid >> 2, col = (tid & 3) * 8;                              \
        gld16(Bt + (size_t)(n0 + row) * K + (K0) + col, BsP(BUF) + tid * 8);  \
    }                                                                         \
} while (0)

    GSTAGE(0, 0);                         // prologue: stage K-step 0
    const int nk = K >> 5;
    for (int jk = 0; jk < nk; jk++) {
        const int cb = jk & 1;
        __syncthreads();                  // stage(jk) visible; buf cb^1 free
        if (jk + 1 < nk) { GSTAGE(cb ^ 1, (jk + 1) * 32); }
        bf16x8 af[4], bfm[NF];
        for (int mi = 0; mi < 4; mi++)
            af[mi] = *(const bf16x8*)(AsP(cb) + (wm * 64 + mi * 16 + l16) * 32 + quad * 8);
        for (int ni = 0; ni < NF; ni++)
            bfm[ni] = *(const bf16x8*)(BsP(cb) + ((BN / 2) * wn + ni * 16 + l16) * 32 + quad * 8);
        for (int mi = 0; mi < 4; mi++)
            for (int ni = 0; ni < NF; ni++)
                acc[mi][ni] = __builtin_amdgcn_mfma_f32_16x16x32_bf16(
                    af[mi], bfm[ni], acc[mi][ni], 0, 0, 0);
    }
#undef GSTAGE

    if constexpr (MODE == 0) {
        const float SCQ = 0.125f * 1.44269504f;
        const int which = n0 >> 10;                 // block-uniform (n0 % 128 == 0)
        if (which < 2) {                            // q / k: scatter to [bh][T][D]
            for (int mi = 0; mi < 4; mi++)
                for (int ni = 0; ni < 4; ni++)
                    for (int r = 0; r < 4; r++) {
                        int row = m0 + wm * 64 + mi * 16 + quad * 4 + r;
                        int col = n0 + wn * 64 + ni * 16 + l16;
                        int h = (col >> 6) & 15, d = col & 63;
                        int b = row >> 11, t = row & 2047;
                        size_t off = ((size_t)(b * HH + h) * TT + t) * DD + d;
                        float val = acc[mi][ni][r];
                        if (which == 0) val *= SCQ;
                        (which == 0 ? Cq : Ck)[off] = f2b(val);
                    }
        } else {                                    // v: LDS-transpose -> vt[bh][D][T]
            __syncthreads();                        // staging buffers now dead
            for (int mi = 0; mi < 4; mi++)
                for (int ni = 0; ni < 4; ni++)
                    for (int r = 0; r < 4; r++) {
                        int cl = wn * 64 + ni * 16 + l16;
                        int tl = wm * 64 + mi * 16 + quad * 4 + r;
                        smem[cl * 136 + tl] = f2b(acc[mi][ni][r]);
                    }
            __syncthreads();
            const int b = m0 >> 11, t0l = m0 & 2047;
            const int c0 = n0 - 2048;
            for (int j = 0; j < 8; j++) {
                int idx = j * 256 + tid;
                int cl = idx >> 4, ch = idx & 15;
                int cg = c0 + cl, h = cg >> 6, d = cg & 63;
                uint4 val = *(const uint4*)&smem[cl * 136 + ch * 8];
                *(uint4*)&Cv[((size_t)(b * HH + h) * DD + d) * TT + t0l + ch * 8] = val;
            }
        }
    } else {
        for (int mi = 0; mi < 4; mi++)
            for (int ni = 0; ni < NF; ni++)
                for (int r = 0; r < 4; r++) {
                    int row = m0 + wm * 64 + mi * 16 + quad * 4 + r;
                    int col = n0 + wn * 32 + ni * 16 + l16;
                    Cout[(size_t)row * N + col] = acc[mi][ni][r];
                }
    }
#undef AsP
#undef BsP
}

// ---------------- flash attention v8 (best measured; session noise 58-67 us) ----------------
// Grid (bh=32, y=32); XCD = bh%8 keeps each head's K/V in one XCD L2.
// K AND V double-buffered, ONE __syncthreads per pass; K[jk+1] and V[jk+1]
// staged immediately after it into the buffers last read in pass jk-1.
// XOR swizzle slot^=(row&7) on global source + ds_read (both-sides, LDS linear
// for the DMA). LDS: 32K (K dbuf) + 32K (V dbuf) + 16K (Ps) = 80 KB.
// __launch_bounds__(256,2): min-waves>=3 forces 64 VGPR + ~28MB scratch spill
// (R1/R5 lesson). Measured: VGPR 88, no spill.
__global__ __launch_bounds__(256, 2) void attn_k(const u16* __restrict__ Q,
                                                 const u16* __restrict__ Kb,
                                                 const u16* __restrict__ Vtg,
                                                 u16* __restrict__ Y) {
    __shared__ __attribute__((aligned(16))) u16 Ks[2][128 * 64];  // 32 KB
    __shared__ __attribute__((aligned(16))) u16 Vs[2][64 * 128];  // 32 KB
    __shared__ __attribute__((aligned(16))) u16 Ps[4][16 * 128];  // 16 KB
    const int tid  = threadIdx.x;
    const int lane = tid & 63, w = tid >> 6;
    const int quad = lane >> 4, l16 = lane & 15;
    const int bh = blockIdx.x;                 // 0..31 -> XCD = bh%8
    const int y  = blockIdx.y;                 // 0..31
    // work table balances causal load: work = nkt = (sb>>1)+1
    const int rowi = (y >> 1) & 3, coli = y >> 3;
    const int basew = ((coli & 1) ? 9 : 16) - ((coli >> 1) << 3);
    const int work = basew + ((coli & 1) ? rowi : -rowi);
    const int sb = 2 * (work - 1) + (y & 1);
    const int nkt = work;
    const size_t base  = (size_t)bh * TT * DD;
    const size_t baseV = (size_t)bh * DD * TT;

    // per-lane staging offsets: 4 rounds x 256 lanes cover 1024 16B-slots/tile.
    // content swizzle: LDS slot s of row holds global col-group s^(row&7).
    int ksidx[4], koff[4], voff[4];
    for (int r = 0; r < 4; r++) {
        int sidx = r * 256 + tid;
        ksidx[r] = sidx;
        int kr = sidx >> 3, ksl = sidx & 7;
        koff[r] = kr * 64 + ((ksl ^ (kr & 7)) << 3);
        int vr = sidx >> 4, vsl = sidx & 15;
        voff[r] = vr * TT + ((vsl ^ (vr & 7)) << 3);
    }
    const u16* kg = Kb + base;      // + jk*8192 + koff[r]
    const u16* vg = Vtg + baseV;    // + jk*128  + voff[r]

    // prologue: stage tile 0
    for (int r = 0; r < 4; r++) gld16(kg + koff[r], &Ks[0][ksidx[r] * 8]);
    for (int r = 0; r < 4; r++) gld16(vg + voff[r], &Vs[0][ksidx[r] * 8]);

    // Q fragments (A-layout, pre-scaled by 0.125*log2e in gemm0 epilogue)
    bf16x8 qf[2];
    for (int kk = 0; kk < 2; kk++)
        qf[kk] = *(const bf16x8*)(Q + base +
            (size_t)(sb * 64 + w * 16 + l16) * DD + kk * 32 + quad * 8);

    // ds_read swizzled slot offsets (u16 elements)
    const int swx = (l16 & 7);
    const int swk0 = ((quad ^ swx) << 3);
    const int swk1 = (((4 + quad) ^ swx) << 3);

    float mst[4], lst[4];
    f32x4 oacc[4];
    for (int r = 0; r < 4; r++) { mst[r] = -1e30f; lst[r] = 0.f; }
    for (int nd = 0; nd < 4; nd++)
        for (int e = 0; e < 4; e++) oacc[nd][e] = 0.f;

    for (int jk = 0; jk < nkt; jk++) {
        const int cb = jk & 1;
        __syncthreads();   // ONE barrier/pass: stage(jk) visible; buffers cb^1 free

        // stage next K+V tiles (full pass of cover before next barrier's drain)
        if (jk + 1 < nkt) {
            const u16* kn = kg + (size_t)(jk + 1) * (128 * DD);
            const u16* vn = vg + (size_t)(jk + 1) * 128;
            for (int r = 0; r < 4; r++)
                gld16(kn + koff[r], &Ks[cb ^ 1][ksidx[r] * 8]);
            for (int r = 0; r < 4; r++)
                gld16(vn + voff[r], &Vs[cb ^ 1][ksidx[r] * 8]);
        }

        // ---- S = Q K^T from LDS (swizzled ds_read_b128) ----
        f32x4 s[8];
        for (int ni = 0; ni < 8; ni++)
            for (int e = 0; e < 4; e++) s[ni][e] = 0.f;
        {
            bf16x8 kfa[8];
            for (int ni = 0; ni < 8; ni++)
                kfa[ni] = *(const bf16x8*)&Ks[cb][(ni * 16 + l16) * 64 + swk0];
            for (int ni = 0; ni < 8; ni++)
                s[ni] = __builtin_amdgcn_mfma_f32_16x16x32_bf16(
                    qf[0], kfa[ni], s[ni], 0, 0, 0);
        }
        {
            bf16x8 kfa[8];
            for (int ni = 0; ni < 8; ni++)
                kfa[ni] = *(const bf16x8*)&Ks[cb][(ni * 16 + l16) * 64 + swk1];
            for (int ni = 0; ni < 8; ni++)
                s[ni] = __builtin_amdgcn_mfma_f32_16x16x32_bf16(
                    qf[1], kfa[ni], s[ni], 0, 0, 0);
        }

        // ---- online softmax (log2 domain) + Ps write ----
        if (jk == (sb >> 1)) {                 // diagonal tile: causal mask
            int row0 = sb * 64 + w * 16 + quad * 4;
            int col0 = jk * 128 + l16;
            for (int ni = 0; ni < 8; ni++)
                for (int r = 0; r < 4; r++)
                    if (col0 + ni * 16 > row0 + r) s[ni][r] = -1e30f;
        }
        float alpha[4];
        for (int r = 0; r < 4; r++) {
            float mx = s[0][r];
            for (int ni = 1; ni < 8; ni++) mx = fmaxf(mx, s[ni][r]);
            for (int off = 8; off >= 1; off >>= 1)
                mx = fmaxf(mx, __shfl_xor(mx, off));
            float mn = fmaxf(mst[r], mx);
            alpha[r] = __builtin_amdgcn_exp2f(mst[r] - mn);
            mst[r] = mn;
        }
        float rs[4] = {0.f, 0.f, 0.f, 0.f};
        for (int ni = 0; ni < 8; ni++)
            for (int r = 0; r < 4; r++) {
                float pv = __builtin_amdgcn_exp2f(s[ni][r] - mst[r]);
                rs[r] += pv;
                int row = quad * 4 + r;
                int cg  = ni * 2 + (l16 >> 3);
                Ps[w][row * 128 + ((cg ^ row) << 3) + (l16 & 7)] = f2b_fast(pv);
            }
        for (int r = 0; r < 4; r++) {
            float sm = rs[r];
            for (int off = 8; off >= 1; off >>= 1)
                sm += __shfl_xor(sm, off);
            lst[r] = lst[r] * alpha[r] + sm;
            for (int nd = 0; nd < 4; nd++) oacc[nd][r] *= alpha[r];
        }

        // ---- O += P V from LDS ----
        for (int kk = 0; kk < 4; kk++) {
            const int swv = (((kk * 4 + quad) ^ swx) << 3);
            bf16x8 vfa[4];
            for (int nd = 0; nd < 4; nd++)
                vfa[nd] = *(const bf16x8*)&Vs[cb][(nd * 16 + l16) * 128 + swv];
            bf16x8 pf = *(const bf16x8*)&Ps[w][l16 * 128 +
                (((kk * 4 + quad) ^ l16) << 3)];
            for (int nd = 0; nd < 4; nd++)
                oacc[nd] = __builtin_amdgcn_mfma_f32_16x16x32_bf16(
                    pf, vfa[nd], oacc[nd], 0, 0, 0);
        }
    }

    for (int nd = 0; nd < 4; nd++)
        for (int r = 0; r < 4; r++) {
            int row = sb * 64 + w * 16 + quad * 4 + r;
            int col = nd * 16 + l16;
            Y[base + (size_t)row * DD + col] = f2b(oacc[nd][r] / lst[r]);
        }
}

extern "C" void kernel_launch(void* const* d_in, const int* in_sizes, int n_in,
                              void* d_out, int out_size, void* d_ws, size_t ws_size,
                              hipStream_t stream) {
    const float* x      = (const float*)d_in[0];   // [2,2048,1024] fp32
    const float* W_attn = (const float*)d_in[1];   // [1024,3072]  fp32
    const float* W_proj = (const float*)d_in[2];   // [1024,1024]  fp32
    float* out = (float*)d_out;                    // [2,2048,1024] fp32

    u16* Wt_attn = (u16*)d_ws;                    // 3072*1024
    u16* Wt_proj = Wt_attn + 3072 * 1024;         // 1024*1024
    u16* xb      = Wt_proj + 1024 * 1024;         // 4096*1024
    u16* q       = xb + (size_t)MM * CC;
    u16* k       = q + (size_t)32 * 2048 * 64;
    u16* vt      = k + (size_t)32 * 2048 * 64;    // [bh][D][T], written by gemm0
    u16* y       = vt + (size_t)32 * 2048 * 64;

    // 4 launches: prep (fused) -> gemm0 (writes q,k,vt) -> attn -> gemm1
    prep_k<<<dim3(4096 + 768 + 256), 256, 0, stream>>>(
        x, xb, W_attn, Wt_attn, W_proj, Wt_proj);
    gemm_k<0><<<dim3((MM / 128) * (3072 / 128)), 256, 0, stream>>>(
        xb, Wt_attn, q, k, vt, nullptr, 3072, 1024);
    attn_k<<<dim3(32, 32), 256, 0, stream>>>(q, k, vt, y);
    gemm_k<1><<<dim3((MM / 128) * (1024 / 64)), 256, 0, stream>>>(
        y, Wt_proj, nullptr, nullptr, nullptr, out, 1024, 1024);
}